// Round 3
// baseline (33.141 us; speedup 1.0000x reference)
//
#include <hip/hip_runtime.h>

#define DEV __device__ __forceinline__

typedef unsigned u32;
typedef u32   u32x2 __attribute__((ext_vector_type(2)));
typedef float f32x2 __attribute__((ext_vector_type(2)));

// ---------- cross-lane xor-shuffle, all-VALU ----------
// B = lane-bit distance. xor1/2/8 -> single DPP. xor4 -> two DPPs
// (quad_perm[3,2,1,0]=xor3, then row_half_mirror=xor7; 3^7=4).
// xor16/xor32 -> permlane{16,32}_swap + runtime-probed select.

template<int B>
DEV float lshfl(float x, bool p32, bool p16) {
    int xi = __float_as_int(x);
    if constexpr (B == 0) {        // quad_perm [1,0,3,2] = xor1
        return __int_as_float(__builtin_amdgcn_update_dpp(xi, xi, 0xB1, 0xF, 0xF, false));
    } else if constexpr (B == 1) { // quad_perm [2,3,0,1] = xor2
        return __int_as_float(__builtin_amdgcn_update_dpp(xi, xi, 0x4E, 0xF, 0xF, false));
    } else if constexpr (B == 2) { // xor4 = xor3 then xor7
        int t = __builtin_amdgcn_update_dpp(xi, xi, 0x1B, 0xF, 0xF, false);   // quad_perm [3,2,1,0]
        return __int_as_float(__builtin_amdgcn_update_dpp(t, t, 0x141, 0xF, 0xF, false)); // row_half_mirror
    } else if constexpr (B == 3) { // row_ror:8 = xor8 within 16-row
        return __int_as_float(__builtin_amdgcn_update_dpp(xi, xi, 0x128, 0xF, 0xF, false));
    } else if constexpr (B == 4) {
#if __has_builtin(__builtin_amdgcn_permlane16_swap)
        u32x2 r = __builtin_amdgcn_permlane16_swap((u32)xi, (u32)xi, false, false);
        return __int_as_float((int)(p16 ? r.x : r.y));
#else
        return __int_as_float(__builtin_amdgcn_ds_swizzle(xi, 0x401F)); // xor16
#endif
    } else {                       // xor32
        u32x2 r = __builtin_amdgcn_permlane32_swap((u32)xi, (u32)xi, false, false);
        return __int_as_float((int)(p32 ? r.x : r.y));
    }
}

// Convention-independent probes: determine which pair element holds the
// OTHER half/row's value.
DEV bool probe32(int lane) {
    u32 p = (u32)((lane >> 5) & 1);
    u32x2 r = __builtin_amdgcn_permlane32_swap(p, p, false, false);
    return r.x == (p ^ 1u);
}
DEV bool probe16(int lane) {
#if __has_builtin(__builtin_amdgcn_permlane16_swap)
    u32 p = (u32)((lane >> 4) & 1);
    u32x2 r = __builtin_amdgcn_permlane16_swap(p, p, false, false);
    return r.x == (p ^ 1u);
#else
    return false;
#endif
}

// ---------- register-pair (bits 6,7) primitives ----------

DEV void rx_pair(f32x2& a, f32x2& b, float c, float s) {
    // a' = c a - i s b ; b' = c b - i s a
    f32x2 na = { fmaf(c, a.x,  s * b.y), fmaf(c, a.y, -s * b.x) };
    f32x2 nb = { fmaf(c, b.x,  s * a.y), fmaf(c, b.y, -s * a.x) };
    a = na; b = nb;
}

DEV void ry_pair(f32x2& a, f32x2& b, float c, float s) {
    // a' = c a - s b ; b' = s a + c b   (component-parallel -> pk)
    f32x2 c2 = { c, c }, sp = { s, s }, sn = { -s, -s };
    f32x2 na = __builtin_elementwise_fma(c2, a, sn * b);
    f32x2 nb = __builtin_elementwise_fma(c2, b, sp * a);
    a = na; b = nb;
}

DEV void rz_amp(f32x2& a, float c, float ss) {
    // *(c + i ss)
    f32x2 n = { fmaf(c, a.x, -(ss * a.y)), fmaf(c, a.y, ss * a.x) };
    a = n;
}

// ---------- gates on flat-index bit B (B = 7 - qubit) ----------
// layout: amp idx = k*64 + lane; bits 0..5 = lane bits, 6 = k bit0, 7 = k bit1
// state: v[k] = (re, im)

template<int B>
DEV void apply_rx(f32x2 (&v)[4], int lane, bool p32, bool p16, float c, float s) {
    if constexpr (B == 7) {
        rx_pair(v[0], v[2], c, s); rx_pair(v[1], v[3], c, s);
    } else if constexpr (B == 6) {
        rx_pair(v[0], v[1], c, s); rx_pair(v[2], v[3], c, s);
    } else {
        f32x2 c2 = { c, c }, m = { s, -s };
#pragma unroll
        for (int k = 0; k < 4; ++k) {
            f32x2 t = { lshfl<B>(v[k].y, p32, p16), lshfl<B>(v[k].x, p32, p16) }; // (pi, pr)
            v[k] = __builtin_elementwise_fma(c2, v[k], t * m); // re+=s*pi, im-=s*pr
        }
    }
}

template<int B>
DEV void apply_ry(f32x2 (&v)[4], int lane, bool p32, bool p16, float c, float s) {
    if constexpr (B == 7) {
        ry_pair(v[0], v[2], c, s); ry_pair(v[1], v[3], c, s);
    } else if constexpr (B == 6) {
        ry_pair(v[0], v[1], c, s); ry_pair(v[2], v[3], c, s);
    } else {
        float ssel = ((lane >> B) & 1) ? s : -s;
        f32x2 c2 = { c, c }, m = { ssel, ssel };
#pragma unroll
        for (int k = 0; k < 4; ++k) {
            f32x2 t = { lshfl<B>(v[k].x, p32, p16), lshfl<B>(v[k].y, p32, p16) }; // (pr, pi)
            v[k] = __builtin_elementwise_fma(c2, v[k], t * m);
        }
    }
}

template<int B>
DEV void apply_rz(f32x2 (&v)[4], int lane, float c, float s) {
    if constexpr (B == 7) {
        rz_amp(v[0], c, -s); rz_amp(v[1], c, -s);
        rz_amp(v[2], c,  s); rz_amp(v[3], c,  s);
    } else if constexpr (B == 6) {
        rz_amp(v[0], c, -s); rz_amp(v[1], c,  s);
        rz_amp(v[2], c, -s); rz_amp(v[3], c,  s);
    } else {
        float ss = ((lane >> B) & 1) ? s : -s;
#pragma unroll
        for (int k = 0; k < 4; ++k) rz_amp(v[k], c, ss);
    }
}

template<int BC, int BT>
DEV void apply_cnot(f32x2 (&v)[4], int lane, bool p32, bool p16) {
    if constexpr (BC == 7 && BT == 6) {
        f32x2 t = v[2]; v[2] = v[3]; v[3] = t;   // register rename
    } else if constexpr (BC == 6) {
        // ctrl = k bit0 (k=1,3 always on): unconditional partner swap on bit BT
        v[1] = f32x2{ lshfl<BT>(v[1].x, p32, p16), lshfl<BT>(v[1].y, p32, p16) };
        v[3] = f32x2{ lshfl<BT>(v[3].x, p32, p16), lshfl<BT>(v[3].y, p32, p16) };
    } else {
        bool ctrl = (lane >> BC) & 1;
#pragma unroll
        for (int k = 0; k < 4; ++k) {
            float pr = lshfl<BT>(v[k].x, p32, p16);
            float pi = lshfl<BT>(v[k].y, p32, p16);
            v[k].x = ctrl ? pr : v[k].x;
            v[k].y = ctrl ? pi : v[k].y;
        }
    }
}

// ---------- uniform coefficient broadcast (VALU readlane, no memory) ----------

DEV float rl(float v, int idx) {
    return __int_as_float(__builtin_amdgcn_readlane(__float_as_int(v), idx));
}

// ---------- main: one wave per batch element, single fused kernel ----------

__global__ __launch_bounds__(256) void qa_sim(
    const float* __restrict__ x, const float* __restrict__ params,
    float* __restrict__ out, int batch)
{
    int tid  = blockIdx.x * 256 + threadIdx.x;
    int b    = tid >> 6;
    int lane = threadIdx.x & 63;
    if (b >= batch) return;

    bool p32 = probe32(lane);
    bool p16 = probe16(lane);

    // per-lane coefficient table: lanes 0..47 -> params, 48..55 -> this batch's x
    float pv = 0.f;
    if (lane < 48)      pv = params[lane];
    else if (lane < 56) pv = x[b * 8 + (lane - 48)];
    float th = pv * 0.5f;
    float cv = __cosf(th);
    float sv = __sinf(th);

    f32x2 v[4];
    v[0] = (lane == 0) ? f32x2{1.f, 0.f} : f32x2{0.f, 0.f};
    v[1] = f32x2{0.f, 0.f}; v[2] = f32x2{0.f, 0.f}; v[3] = f32x2{0.f, 0.f};

    // ---- data encoding: RX(x[b,i]) on qubit i (bit 7-i) ----
#define ENC(i) apply_rx<7 - (i)>(v, lane, p32, p16, rl(cv, 48 + (i)), rl(sv, 48 + (i)));
    ENC(0) ENC(1) ENC(2) ENC(3) ENC(4) ENC(5) ENC(6) ENC(7)
#undef ENC

    // ---- variational layers: params[l][i][{RY,RZ,RX}] ----
#define VQ(l, i) { const int j = (l) * 24 + (i) * 3;                        \
                   apply_ry<7 - (i)>(v, lane, p32, p16, rl(cv, j), rl(sv, j)); \
                   apply_rz<7 - (i)>(v, lane, rl(cv, j + 1), rl(sv, j + 1)); }
#define CN(i)    apply_cnot<7 - (i), 6 - (i)>(v, lane, p32, p16);
#define RXQ(l,i) { const int j = (l) * 24 + (i) * 3 + 2;                    \
                   apply_rx<7 - (i)>(v, lane, p32, p16, rl(cv, j), rl(sv, j)); }
#define LAYER(l) \
    VQ(l,0) CN(0) VQ(l,1) CN(1) VQ(l,2) CN(2) VQ(l,3) CN(3) \
    VQ(l,4) CN(4) VQ(l,5) CN(5) VQ(l,6) CN(6) VQ(l,7)       \
    RXQ(l,0) RXQ(l,1) RXQ(l,2) RXQ(l,3) RXQ(l,4) RXQ(l,5) RXQ(l,6) RXQ(l,7)

    LAYER(0)
    LAYER(1)
#undef LAYER
#undef RXQ
#undef CN
#undef VQ

    // ---- <Z_i> readout ----
    float p0 = fmaf(v[0].x, v[0].x, v[0].y * v[0].y);
    float p1 = fmaf(v[1].x, v[1].x, v[1].y * v[1].y);
    float p2 = fmaf(v[2].x, v[2].x, v[2].y * v[2].y);
    float p3 = fmaf(v[3].x, v[3].x, v[3].y * v[3].y);

    float z0 = (p0 + p1) - (p2 + p3);   // qubit0 = bit7 = k bit1
    float z1 = (p0 - p1) + (p2 - p3);   // qubit1 = bit6 = k bit0
    float A  = (p0 + p1) + (p2 + p3);   // total prob, per-lane

    // full reductions for z0, z1
    z0 += lshfl<0>(z0, p32, p16); z1 += lshfl<0>(z1, p32, p16);
    z0 += lshfl<1>(z0, p32, p16); z1 += lshfl<1>(z1, p32, p16);
    z0 += lshfl<2>(z0, p32, p16); z1 += lshfl<2>(z1, p32, p16);
    z0 += lshfl<3>(z0, p32, p16); z1 += lshfl<3>(z1, p32, p16);
    z0 += lshfl<4>(z0, p32, p16); z1 += lshfl<4>(z1, p32, p16);
    z0 += lshfl<5>(z0, p32, p16); z1 += lshfl<5>(z1, p32, p16);

    // pruned Walsh-Hadamard on A: signed sum for each lane bit b
    float S = A, P, D0, D1, D2, D3, D4, D5;
    P = lshfl<0>(S, p32, p16); D0 = S - P; S += P;
    P = lshfl<1>(S, p32, p16); D1 = S - P; S += P;
    P = lshfl<2>(S, p32, p16); D2 = S - P; S += P;
    P = lshfl<3>(S, p32, p16); D3 = S - P; S += P;
    P = lshfl<4>(S, p32, p16); D4 = S - P; S += P;
    P = lshfl<5>(S, p32, p16); D5 = S - P;

    D0 += lshfl<1>(D0, p32, p16); D0 += lshfl<2>(D0, p32, p16);
    D0 += lshfl<3>(D0, p32, p16); D0 += lshfl<4>(D0, p32, p16); D0 += lshfl<5>(D0, p32, p16);
    D1 += lshfl<2>(D1, p32, p16); D1 += lshfl<3>(D1, p32, p16);
    D1 += lshfl<4>(D1, p32, p16); D1 += lshfl<5>(D1, p32, p16);
    D2 += lshfl<3>(D2, p32, p16); D2 += lshfl<4>(D2, p32, p16); D2 += lshfl<5>(D2, p32, p16);
    D3 += lshfl<4>(D3, p32, p16); D3 += lshfl<5>(D3, p32, p16);
    D4 += lshfl<5>(D4, p32, p16);

    if (lane == 0) {
        // qubit i (2..7) = lane bit 7-i  ->  out[7-b] = D_b
        float4* o = (float4*)(out + b * 8);
        o[0] = make_float4(z0, z1, D5, D4);
        o[1] = make_float4(D3, D2, D1, D0);
    }
}

extern "C" void kernel_launch(void* const* d_in, const int* in_sizes, int n_in,
                              void* d_out, int out_size, void* d_ws, size_t ws_size,
                              hipStream_t stream) {
    const float* x      = (const float*)d_in[0];   // (BATCH, 8)
    const float* params = (const float*)d_in[1];   // (2, 8, 3) = 48
    float* out = (float*)d_out;

    int batch  = in_sizes[0] / 8;
    int blocks = (batch * 64 + 255) / 256;
    qa_sim<<<blocks, 256, 0, stream>>>(x, params, out, batch);
}

// Round 4
// 30.126 us; speedup vs baseline: 1.1001x; 1.1001x over previous
//
#include <hip/hip_runtime.h>

#define DEV __device__ __forceinline__

typedef unsigned u32;
typedef u32 u32x2 __attribute__((ext_vector_type(2)));

// ---------- cross-lane xor-shuffle ----------
// xor1/2/8 -> single DPP (VALU). xor4/16 -> imm-mode ds_swizzle (1 DS op, no
// addr VGPR). xor32 -> permlane32_swap (VALU) + runtime-probed select.

template<int B>
DEV float lshfl(float x, bool px) {
    int xi = __float_as_int(x);
    if constexpr (B == 0) {        // quad_perm [1,0,3,2] = xor1
        return __int_as_float(__builtin_amdgcn_update_dpp(xi, xi, 0xB1, 0xF, 0xF, false));
    } else if constexpr (B == 1) { // quad_perm [2,3,0,1] = xor2
        return __int_as_float(__builtin_amdgcn_update_dpp(xi, xi, 0x4E, 0xF, 0xF, false));
    } else if constexpr (B == 2) { // ds_swizzle xor4
        return __int_as_float(__builtin_amdgcn_ds_swizzle(xi, 0x101F));
    } else if constexpr (B == 3) { // row_ror:8 = xor8 within 16-lane row
        return __int_as_float(__builtin_amdgcn_update_dpp(xi, xi, 0x128, 0xF, 0xF, false));
    } else if constexpr (B == 4) { // ds_swizzle xor16
        return __int_as_float(__builtin_amdgcn_ds_swizzle(xi, 0x401F));
    } else {                       // xor32: permlane32_swap + select
        u32x2 r = __builtin_amdgcn_permlane32_swap((u32)xi, (u32)xi, false, false);
        return __int_as_float((int)(px ? r.x : r.y));
    }
}

// Convention-independent probe: which pair element holds the OTHER half's value.
DEV bool probe32(int lane) {
    u32 p = (u32)((lane >> 5) & 1);
    u32x2 r = __builtin_amdgcn_permlane32_swap(p, p, false, false);
    return r.x == (p ^ 1u);
}

// ---------- complex pair primitives (fp32) ----------

DEV void rx_pair(float& r0, float& i0, float& r1, float& i1, float c, float s) {
    float nr0 = fmaf(c, r0,  s * i1);
    float ni0 = fmaf(c, i0, -s * r1);
    float nr1 = fmaf(c, r1,  s * i0);
    float ni1 = fmaf(c, i1, -s * r0);
    r0 = nr0; i0 = ni0; r1 = nr1; i1 = ni1;
}

DEV void ry_pair(float& r0, float& i0, float& r1, float& i1, float c, float s) {
    float nr0 = fmaf(c, r0, -s * r1);
    float ni0 = fmaf(c, i0, -s * i1);
    float nr1 = fmaf(c, r1,  s * r0);
    float ni1 = fmaf(c, i1,  s * i0);
    r0 = nr0; i0 = ni0; r1 = nr1; i1 = ni1;
}

DEV void rz_amp(float& r, float& i, float c, float ss) {
    float nr = fmaf(c, r, -ss * i);
    float ni = fmaf(c, i,  ss * r);
    r = nr; i = ni;
}

// ---------- gates on flat-index bit B (B = 7 - qubit) ----------
// layout: amp idx = k*64 + lane; bits 0..5 = lane bits, 6 = k bit0, 7 = k bit1

template<int B>
DEV void apply_rx(float (&re)[4], float (&im)[4], int lane, bool px, float c, float s) {
    if constexpr (B == 7) {
        rx_pair(re[0], im[0], re[2], im[2], c, s);
        rx_pair(re[1], im[1], re[3], im[3], c, s);
    } else if constexpr (B == 6) {
        rx_pair(re[0], im[0], re[1], im[1], c, s);
        rx_pair(re[2], im[2], re[3], im[3], c, s);
    } else {
#pragma unroll
        for (int k = 0; k < 4; ++k) {
            float pr = lshfl<B>(re[k], px);
            float pi = lshfl<B>(im[k], px);
            re[k] = fmaf(c, re[k],  s * pi);   // RX symmetric: no hi/lo branch
            im[k] = fmaf(c, im[k], -s * pr);
        }
    }
}

template<int B>
DEV void apply_ry(float (&re)[4], float (&im)[4], int lane, bool px, float c, float s) {
    if constexpr (B == 7) {
        ry_pair(re[0], im[0], re[2], im[2], c, s);
        ry_pair(re[1], im[1], re[3], im[3], c, s);
    } else if constexpr (B == 6) {
        ry_pair(re[0], im[0], re[1], im[1], c, s);
        ry_pair(re[2], im[2], re[3], im[3], c, s);
    } else {
        float ssel = ((lane >> B) & 1) ? s : -s;
#pragma unroll
        for (int k = 0; k < 4; ++k) {
            float pr = lshfl<B>(re[k], px);
            float pi = lshfl<B>(im[k], px);
            re[k] = fmaf(c, re[k], ssel * pr);
            im[k] = fmaf(c, im[k], ssel * pi);
        }
    }
}

template<int B>
DEV void apply_rz(float (&re)[4], float (&im)[4], int lane, float c, float s) {
    if constexpr (B == 7) {
        rz_amp(re[0], im[0], c, -s); rz_amp(re[1], im[1], c, -s);
        rz_amp(re[2], im[2], c,  s); rz_amp(re[3], im[3], c,  s);
    } else if constexpr (B == 6) {
        rz_amp(re[0], im[0], c, -s); rz_amp(re[1], im[1], c,  s);
        rz_amp(re[2], im[2], c, -s); rz_amp(re[3], im[3], c,  s);
    } else {
        float ss = ((lane >> B) & 1) ? s : -s;
#pragma unroll
        for (int k = 0; k < 4; ++k) rz_amp(re[k], im[k], c, ss);
    }
}

template<int BC, int BT>
DEV void apply_cnot(float (&re)[4], float (&im)[4], int lane, bool px) {
    if constexpr (BC == 7 && BT == 6) {
        float tr = re[2], ti = im[2];
        re[2] = re[3]; im[2] = im[3];
        re[3] = tr;    im[3] = ti;
    } else if constexpr (BC == 6) {
        // ctrl = k bit0 (k=1,3 always on): unconditional swap across lane bit BT
        re[1] = lshfl<BT>(re[1], px); im[1] = lshfl<BT>(im[1], px);
        re[3] = lshfl<BT>(re[3], px); im[3] = lshfl<BT>(im[3], px);
    } else {
        bool ctrl = (lane >> BC) & 1;
#pragma unroll
        for (int k = 0; k < 4; ++k) {
            float pr = lshfl<BT>(re[k], px);
            float pi = lshfl<BT>(im[k], px);
            re[k] = ctrl ? pr : re[k];
            im[k] = ctrl ? pi : im[k];
        }
    }
}

// ---------- prep: cos/sin of 48 shared params into ws ----------

__global__ void qa_prep(const float* __restrict__ params, float* __restrict__ gc, int n) {
    int t = blockIdx.x * blockDim.x + threadIdx.x;
    if (t < n) {
        float th = params[t] * 0.5f;
        gc[2 * t]     = cosf(th);
        gc[2 * t + 1] = sinf(th);
    }
}

// ---------- main: one wave per batch element ----------
// __launch_bounds__(256, 8): pin 8 waves/SIMD -> VGPR cap 64 -> full occupancy.

__global__ __launch_bounds__(256, 8) void qa_sim(
    const float* __restrict__ x, const float* __restrict__ gc,
    float* __restrict__ out, int batch)
{
    int tid  = blockIdx.x * 256 + threadIdx.x;
    int b    = tid >> 6;
    int lane = threadIdx.x & 63;
    if (b >= batch) return;

    bool px = probe32(lane);

    float re[4], im[4];
    re[0] = (lane == 0) ? 1.f : 0.f;
    re[1] = re[2] = re[3] = 0.f;
    im[0] = im[1] = im[2] = im[3] = 0.f;

    const float* xb = x + b * 8;

    // ---- data encoding: RX(x[b,i]) on qubit i (bit 7-i) ----
#define ENC(i) { float s_, c_; __sincosf(xb[i] * 0.5f, &s_, &c_); \
                 apply_rx<7 - (i)>(re, im, lane, px, c_, s_); }
    ENC(0) ENC(1) ENC(2) ENC(3) ENC(4) ENC(5) ENC(6) ENC(7)
#undef ENC

    // ---- variational layers ----
#define VQ(l, i) { const float* g = gc + 2 * ((l) * 24 + (i) * 3); \
                   apply_ry<7 - (i)>(re, im, lane, px, g[0], g[1]); \
                   apply_rz<7 - (i)>(re, im, lane, g[2], g[3]); }
#define CN(i)    apply_cnot<7 - (i), 6 - (i)>(re, im, lane, px);
#define RXQ(l,i) { const float* g = gc + 2 * ((l) * 24 + (i) * 3 + 2); \
                   apply_rx<7 - (i)>(re, im, lane, px, g[0], g[1]); }
#define LAYER(l) \
    VQ(l,0) CN(0) VQ(l,1) CN(1) VQ(l,2) CN(2) VQ(l,3) CN(3) \
    VQ(l,4) CN(4) VQ(l,5) CN(5) VQ(l,6) CN(6) VQ(l,7)       \
    RXQ(l,0) RXQ(l,1) RXQ(l,2) RXQ(l,3) RXQ(l,4) RXQ(l,5) RXQ(l,6) RXQ(l,7)

    LAYER(0)
    LAYER(1)
#undef LAYER
#undef RXQ
#undef CN
#undef VQ

    // ---- <Z_i> readout ----
    float p0 = fmaf(re[0], re[0], im[0] * im[0]);
    float p1 = fmaf(re[1], re[1], im[1] * im[1]);
    float p2 = fmaf(re[2], re[2], im[2] * im[2]);
    float p3 = fmaf(re[3], re[3], im[3] * im[3]);

    float z0 = (p0 + p1) - (p2 + p3);   // qubit0 = bit7 = k bit1
    float z1 = (p0 - p1) + (p2 - p3);   // qubit1 = bit6 = k bit0
    float A  = (p0 + p1) + (p2 + p3);   // total prob per lane

    z0 += lshfl<0>(z0, px); z1 += lshfl<0>(z1, px);
    z0 += lshfl<1>(z0, px); z1 += lshfl<1>(z1, px);
    z0 += lshfl<2>(z0, px); z1 += lshfl<2>(z1, px);
    z0 += lshfl<3>(z0, px); z1 += lshfl<3>(z1, px);
    z0 += lshfl<4>(z0, px); z1 += lshfl<4>(z1, px);
    z0 += lshfl<5>(z0, px); z1 += lshfl<5>(z1, px);

    // pruned Walsh-Hadamard on A: D_b = signed sum over lane bit b
    float S = A, P, D0, D1, D2, D3, D4, D5;
    P = lshfl<0>(S, px); D0 = S - P; S += P;
    P = lshfl<1>(S, px); D1 = S - P; S += P;
    P = lshfl<2>(S, px); D2 = S - P; S += P;
    P = lshfl<3>(S, px); D3 = S - P; S += P;
    P = lshfl<4>(S, px); D4 = S - P; S += P;
    P = lshfl<5>(S, px); D5 = S - P;

    D0 += lshfl<1>(D0, px); D0 += lshfl<2>(D0, px);
    D0 += lshfl<3>(D0, px); D0 += lshfl<4>(D0, px); D0 += lshfl<5>(D0, px);
    D1 += lshfl<2>(D1, px); D1 += lshfl<3>(D1, px);
    D1 += lshfl<4>(D1, px); D1 += lshfl<5>(D1, px);
    D2 += lshfl<3>(D2, px); D2 += lshfl<4>(D2, px); D2 += lshfl<5>(D2, px);
    D3 += lshfl<4>(D3, px); D3 += lshfl<5>(D3, px);
    D4 += lshfl<5>(D4, px);

    if (lane == 0) {
        // qubit i (2..7) = lane bit 7-i -> D_{7-i}
        float4* o = (float4*)(out + b * 8);
        o[0] = make_float4(z0, z1, D5, D4);
        o[1] = make_float4(D3, D2, D1, D0);
    }
}

extern "C" void kernel_launch(void* const* d_in, const int* in_sizes, int n_in,
                              void* d_out, int out_size, void* d_ws, size_t ws_size,
                              hipStream_t stream) {
    const float* x      = (const float*)d_in[0];   // (BATCH, 8)
    const float* params = (const float*)d_in[1];   // (2, 8, 3) = 48
    float* out = (float*)d_out;
    float* gc  = (float*)d_ws;                     // 96 floats of (cos,sin)

    int batch   = in_sizes[0] / 8;
    int nparams = in_sizes[1];                     // 48

    qa_prep<<<1, 64, 0, stream>>>(params, gc, nparams);

    int blocks = (batch * 64 + 255) / 256;
    qa_sim<<<blocks, 256, 0, stream>>>(x, gc, out, batch);
}